// Round 22
// baseline (409.998 us; speedup 1.0000x reference)
//
#include <hip/hip_runtime.h>
#include <math.h>

// L=32768 lines, M=8 neighbors, B=8192 blocks, LIN=BIN=768, H=512, NH=8, DH=64

typedef unsigned short u16;
typedef unsigned int u32;
using bf16x8 = __attribute__((ext_vector_type(8))) __bf16;
using u16x8  = __attribute__((ext_vector_type(8))) u16;
using f32x4  = __attribute__((ext_vector_type(4))) float;

__device__ __forceinline__ u16 f2bf(float f) {
    u32 u = __builtin_bit_cast(u32, f);
    u32 r = u + 0x7fffu + ((u >> 16) & 1u);
    return (u16)(r >> 16);
}
__device__ __forceinline__ float bf2f(u16 h) {
    return __builtin_bit_cast(float, (u32)h << 16);
}
__device__ __forceinline__ float gelu_exact(float x) {
    return 0.5f * x * (1.0f + erff(x * 0.70710678118654752440f));
}

// Block-wide reduction of one value across 256 threads (4 waves).
__device__ __forceinline__ float breduce1(float s0, float* sm) {
    #pragma unroll
    for (int off = 32; off > 0; off >>= 1) s0 += __shfl_down(s0, off);
    const int lane = threadIdx.x & 63, w = threadIdx.x >> 6;
    __syncthreads();
    if (lane == 0) sm[w] = s0;
    __syncthreads();
    return sm[0] + sm[1] + sm[2] + sm[3];
}

// ---------------- fused multi-array conversion (weights) ----------------
struct CvtJobs {
    const float* s[5];
    u16* d[5];
    int cum[6];   // cumulative quad counts
};
__global__ __launch_bounds__(256) void cvt_multi(CvtJobs j)
{
    const int g = blockIdx.x * 256 + threadIdx.x;   // quad index
    if (g >= j.cum[5]) return;
    int seg = 0;
    #pragma unroll
    for (int k = 1; k < 5; ++k) seg += (g >= j.cum[k]);
    const int q = g - j.cum[seg];
    const float4 v = *reinterpret_cast<const float4*>(j.s[seg] + q * 4);
    ushort4 o = make_ushort4(f2bf(v.x), f2bf(v.y), f2bf(v.z), f2bf(v.w));
    *reinterpret_cast<ushort4*>(j.d[seg] + q * 4) = o;
}

// ---------------- W2 fold: W2 = p1b @ out_w  (fp32 in, bf16 out) ------------
__global__ __launch_bounds__(256) void fold_w2(
    const float* __restrict__ p1w, const float* __restrict__ outw,
    u16* __restrict__ p1cb)
{
    __shared__ float As[16][65];   // [k][i]
    __shared__ float Bs[16][65];   // [k][j]
    const int tx = threadIdx.x & 15, ty = threadIdx.x >> 4;
    const int i0 = blockIdx.y * 64, j0 = blockIdx.x * 64;
    const int lr = threadIdx.x >> 2;
    const int lc = (threadIdx.x & 3) * 4;
    const int kr = threadIdx.x >> 4;
    const int jc = (threadIdx.x & 15) * 4;
    float acc[4][4] = {};
    for (int k0 = 0; k0 < 512; k0 += 16) {
        const float4 av = *reinterpret_cast<const float4*>(
            p1w + (size_t)(i0 + lr) * 1024 + 512 + k0 + lc);
        As[lc + 0][lr] = av.x; As[lc + 1][lr] = av.y;
        As[lc + 2][lr] = av.z; As[lc + 3][lr] = av.w;
        const float4 bv = *reinterpret_cast<const float4*>(
            outw + (size_t)(k0 + kr) * 512 + j0 + jc);
        Bs[kr][jc + 0] = bv.x; Bs[kr][jc + 1] = bv.y;
        Bs[kr][jc + 2] = bv.z; Bs[kr][jc + 3] = bv.w;
        __syncthreads();
        #pragma unroll
        for (int kk = 0; kk < 16; ++kk) {
            float a[4], b[4];
            #pragma unroll
            for (int i = 0; i < 4; ++i) a[i] = As[kk][ty * 4 + i];
            #pragma unroll
            for (int jj = 0; jj < 4; ++jj) b[jj] = Bs[kk][tx * 4 + jj];
            #pragma unroll
            for (int i = 0; i < 4; ++i)
                #pragma unroll
                for (int jj = 0; jj < 4; ++jj)
                    acc[i][jj] = fmaf(a[i], b[jj], acc[i][jj]);
        }
        __syncthreads();
    }
    #pragma unroll
    for (int i = 0; i < 4; ++i)
        #pragma unroll
        for (int jj = 0; jj < 4; ++jj)
            p1cb[(size_t)(i0 + ty * 4 + i) * 1024 + 512 + j0 + tx * 4 + jj] =
                f2bf(acc[i][jj]);
}

// bias2[i] = p1_b[i] + sum_k p1_w[i][512+k] * out_b[k]
__global__ __launch_bounds__(64) void fold_bias(
    const float* __restrict__ p1w, const float* __restrict__ outb,
    const float* __restrict__ p1b, float* __restrict__ bias2)
{
    const int i = blockIdx.x, lane = threadIdx.x;
    float s = 0.0f;
    #pragma unroll
    for (int k = lane; k < 512; k += 64)
        s += p1w[(size_t)i * 1024 + 512 + k] * outb[k];
    #pragma unroll
    for (int off = 32; off > 0; off >>= 1) s += __shfl_down(s, off);
    if (lane == 0) bias2[i] = s + p1b[i];
}

// ---------------- bf16 MFMA GEMM, dual-job (R20) + fp32-A mode (R21) --------
// Two independent GEMMs packed into one launch: blocks [0,n0) run job0,
// [n0,n0+n1) run job1.
// Per job: 64x128 tile, BK=32, 4 waves, 2-buffer counted-vmcnt pipeline,
// T2 LDS XOR-swizzle (R18, verified), T1 XCD swizzle within job range.
// A_MODE: 0 = bf16 A (gload_lds, inverse-swizzled source)
//         1 = fp32 A read DIRECTLY (R21): 2 reg global_loads/wave/tile,
//             cvt+ds_write into swizzled slot after MFMA (write-late).
//             vmcnt ops/tile = 4 -> steady wait vmcnt(4), last vmcnt(0);
//             lgkmcnt(0) drains the ds_write before the 2nd barrier.
//         2 = two bf16 sources split at column K1 (both gload_lds).
// STATS requires N==512 (nbx==4).
struct GemmJob {
    const u16* A1; const u16* A2; const float* A1f; int K1; int K;
    const u16* W; const float* bias;
    u16* C; int N; float* stats;
    int nbx;     // N/128
    int nwg;     // total blocks (divisible by 8)
};

template<int A_MODE, bool STATS>
__global__ __launch_bounds__(256) void gemm_bf16(
    GemmJob j0, GemmJob j1, int n0)
{
    __shared__ __bf16 As[2 * 64 * 32];     // 8 KB
    __shared__ __bf16 Ws[2 * 128 * 32];    // 16 KB
    const int tid = threadIdx.x;
    const int w = tid >> 6, lane = tid & 63;

    GemmJob jb;
    int orig;
    if ((int)blockIdx.x < n0) { jb = j0; orig = blockIdx.x; }
    else                      { jb = j1; orig = blockIdx.x - n0; }

    // T1 swizzle within the job's block range (nwg divisible by 8)
    const u32 wgid = ((u32)orig & 7u) * ((u32)jb.nwg >> 3) + ((u32)orig >> 3);
    const int bx = (int)(wgid % (u32)jb.nbx);
    const int row0 = (int)(wgid / (u32)jb.nbx) * 64;
    const int col0 = bx * 128;
    const int K = jb.K, K1 = jb.K1, N = jb.N;

    const int wrow = (w >> 1) * 32, wcol = (w & 1) * 64;
    const int fr = lane & 15, fg = lane >> 4;
    const int fgx = fg ^ ((fr >> 1) & 3);   // swizzled 16B-slot index (in [0,4))

    // W staging geometry (128x32 bf16 tile, 2 chunks/wave), swizzled source
    int srow[2], scol[2], soff[2];
    #pragma unroll
    for (int c = 0; c < 2; ++c) {
        const int bo = w * 2048 + c * 1024 + lane * 16;
        srow[c] = bo >> 6;
        const int slot = (bo & 63) >> 4;                 // = lane & 3
        scol[c] = (slot ^ ((srow[c] >> 1) & 3)) * 8;     // in [0,32)
        soff[c] = (w * 2048 + c * 1024) >> 1;
    }
    // A staging geometry, bf16 modes (64x32 tile, 1 gload_lds chunk/wave)
    const int aoA = w * 1024 + lane * 16;
    const int srA = aoA >> 6;
    const int scA = (((aoA & 63) >> 4) ^ ((srA >> 1) & 3)) * 8;  // in [0,32)
    const int sofA = (w * 1024) >> 1;
    // A staging geometry, fp32 mode (reg-staged): thread -> row arF, 8 elems
    const int arF = tid >> 2;
    const int acF = (tid & 3) * 8;
    const int slotF = ((acF >> 3) ^ ((arF >> 1) & 3));   // swizzled LDS slot

    f32x4 acc[2][4] = {};
    float4 avlo, avhi;   // A_MODE==1 in-flight regs

    auto stage_issue = [&](int k0, int buf) {
        if (A_MODE == 1) {
            const float* src = jb.A1f + (size_t)(row0 + arF) * K + k0 + acF;
            avlo = *reinterpret_cast<const float4*>(src);
            avhi = *reinterpret_cast<const float4*>(src + 4);
        } else {
            const u16* asrc;
            if (A_MODE == 2 && k0 >= K1) {
                asrc = jb.A2 + (size_t)(row0 + srA) * (K - K1) + (k0 - K1) + scA;
            } else {
                const int ld = (A_MODE == 2) ? K1 : K;
                asrc = jb.A1 + (size_t)(row0 + srA) * ld + k0 + scA;
            }
            __builtin_amdgcn_global_load_lds(
                (const __attribute__((address_space(1))) u32*)asrc,
                (__attribute__((address_space(3))) u32*)(As + buf * 2048 + sofA),
                16, 0, 0);
        }
        #pragma unroll
        for (int c = 0; c < 2; ++c) {
            const u16* wsrc = jb.W + (size_t)(col0 + srow[c]) * K + k0 + scol[c];
            __builtin_amdgcn_global_load_lds(
                (const __attribute__((address_space(1))) u32*)wsrc,
                (__attribute__((address_space(3))) u32*)(Ws + buf * 4096 + soff[c]),
                16, 0, 0);
        }
    };
    auto stage_write = [&](int buf) {   // A_MODE==1 only: cvt + swizzled ds_write
        u16x8 o;
        o[0] = f2bf(avlo.x); o[1] = f2bf(avlo.y); o[2] = f2bf(avlo.z); o[3] = f2bf(avlo.w);
        o[4] = f2bf(avhi.x); o[5] = f2bf(avhi.y); o[6] = f2bf(avhi.z); o[7] = f2bf(avhi.w);
        *reinterpret_cast<u16x8*>((u16*)As + buf * 2048 + arF * 32 + slotF * 8) = o;
    };

    const int NT = K >> 5;           // >= 16 always here

    stage_issue(0, 0);
    if (A_MODE == 1) {
        stage_write(0);              // compiler waits on avlo/avhi
        asm volatile("s_waitcnt lgkmcnt(0)" ::: "memory");
    }

    int bufc = 0;
    for (int t = 0; t < NT; ++t) {
        if (t + 1 < NT) {
            stage_issue((t + 1) << 5, bufc ^ 1);
            // wait tile t's W complete; t+1's loads stay in flight
            if (A_MODE == 1) asm volatile("s_waitcnt vmcnt(4)" ::: "memory");
            else             asm volatile("s_waitcnt vmcnt(3)" ::: "memory");
        } else {
            asm volatile("s_waitcnt vmcnt(0)" ::: "memory");
        }
        __builtin_amdgcn_s_barrier();          // tile t fully in LDS for all waves
        __builtin_amdgcn_sched_barrier(0);

        bf16x8 af[2], bfr[4];
        #pragma unroll
        for (int m = 0; m < 2; ++m)
            af[m] = *(const bf16x8*)(As + bufc * 2048 + (wrow + m * 16 + fr) * 32 + fgx * 8);
        #pragma unroll
        for (int n = 0; n < 4; ++n)
            bfr[n] = *(const bf16x8*)(Ws + bufc * 4096 + (wcol + n * 16 + fr) * 32 + fgx * 8);
        #pragma unroll
        for (int m = 0; m < 2; ++m)
            #pragma unroll
            for (int n = 0; n < 4; ++n)
                acc[m][n] = __builtin_amdgcn_mfma_f32_16x16x32_bf16(
                    af[m], bfr[n], acc[m][n], 0, 0, 0);

        if (A_MODE == 1 && t + 1 < NT) {
            stage_write(bufc ^ 1);             // compiler waits on avlo/avhi (vmcnt(2))
            asm volatile("s_waitcnt lgkmcnt(0)" ::: "memory");
        }
        __builtin_amdgcn_s_barrier();          // all waves done reading buf t
        bufc ^= 1;
    }

    // bias add (pre-stats, pre-round)
    if (jb.bias) {
        #pragma unroll
        for (int n = 0; n < 4; ++n) {
            const float bvv = jb.bias[col0 + wcol + n * 16 + fr];
            #pragma unroll
            for (int m = 0; m < 2; ++m)
                #pragma unroll
                for (int r = 0; r < 4; ++r)
                    acc[m][n][r] += bvv;
        }
    }

    // C/D layout: col=lane&15, row=(lane>>4)*4+reg  [m89-verified]
    #pragma unroll
    for (int m = 0; m < 2; ++m)
        #pragma unroll
        for (int n = 0; n < 4; ++n) {
            const int col = col0 + wcol + n * 16 + fr;
            #pragma unroll
            for (int r = 0; r < 4; ++r) {
                const int row = row0 + wrow + m * 16 + fg * 4 + r;
                jb.C[(size_t)row * N + col] = f2bf(acc[m][n][r]);
            }
        }

    if (STATS) {
        float ps[2][4], pq[2][4];
        #pragma unroll
        for (int m = 0; m < 2; ++m)
            #pragma unroll
            for (int r = 0; r < 4; ++r) {
                float s = 0.0f, q2 = 0.0f;
                #pragma unroll
                for (int n = 0; n < 4; ++n) {
                    const float v = acc[m][n][r];
                    s += v; q2 = fmaf(v, v, q2);
                }
                ps[m][r] = s; pq[m][r] = q2;
            }
        #pragma unroll
        for (int off = 1; off < 16; off <<= 1)
            #pragma unroll
            for (int m = 0; m < 2; ++m)
                #pragma unroll
                for (int r = 0; r < 4; ++r) {
                    ps[m][r] += __shfl_xor(ps[m][r], off);
                    pq[m][r] += __shfl_xor(pq[m][r], off);
                }
        if (fr == 0) {
            const int cb = bx * 2 + (w & 1);
            #pragma unroll
            for (int m = 0; m < 2; ++m)
                #pragma unroll
                for (int r = 0; r < 4; ++r) {
                    const int row = row0 + wrow + m * 16 + fg * 4 + r;
                    *reinterpret_cast<float2*>(jb.stats + ((size_t)row * 8 + cb) * 2) =
                        make_float2(ps[m][r], pq[m][r]);
                }
        }
    }
}

// ---------------- merged Row LayerNorm (two row ranges, R20) ----------------
__global__ __launch_bounds__(256) void ln_merged(
    u16* __restrict__ X0, const float* __restrict__ st0,
    const float* __restrict__ g0, const float* __restrict__ b0, int n0,
    u16* __restrict__ X1, const float* __restrict__ st1,
    const float* __restrict__ g1, const float* __restrict__ b1)
{
    u16* X; const float* st; const float* g; const float* b; size_t row;
    if ((int)blockIdx.x < n0) { X = X0; st = st0; g = g0; b = b0; row = blockIdx.x; }
    else { X = X1; st = st1; g = g1; b = b1; row = blockIdx.x - n0; }
    float s = 0.0f, q2 = 0.0f;
    #pragma unroll
    for (int cb = 0; cb < 8; ++cb) {
        s  += st[(row * 8 + cb) * 2];
        q2 += st[(row * 8 + cb) * 2 + 1];
    }
    const float mu = s * (1.0f / 512.0f);
    const float var = q2 * (1.0f / 512.0f) - mu * mu;
    const float rs = rsqrtf(var + 1e-5f);
    const int t = threadIdx.x;
    const ushort2 xv = *reinterpret_cast<const ushort2*>(X + row * 512 + 2 * t);
    const float2 gg = *reinterpret_cast<const float2*>(g + 2 * t);
    const float2 bb = *reinterpret_cast<const float2*>(b + 2 * t);
    const float y0 = (bf2f(xv.x) - mu) * rs * gg.x + bb.x;
    const float y1 = (bf2f(xv.y) - mu) * rs * gg.y + bb.y;
    *reinterpret_cast<ushort2*>(X + row * 512 + 2 * t) = make_ushort2(f2bf(y0), f2bf(y1));
}

// ---------------- Row LayerNorm in-place with GELU (h1) ---------------------
__global__ __launch_bounds__(256) void ln_rows_g(
    u16* __restrict__ X, const float* __restrict__ stats,
    const float* __restrict__ g, const float* __restrict__ b)
{
    const size_t row = blockIdx.x;
    float s = 0.0f, q2 = 0.0f;
    #pragma unroll
    for (int cb = 0; cb < 8; ++cb) {
        s  += stats[(row * 8 + cb) * 2];
        q2 += stats[(row * 8 + cb) * 2 + 1];
    }
    const float mu = s * (1.0f / 512.0f);
    const float var = q2 * (1.0f / 512.0f) - mu * mu;
    const float rs = rsqrtf(var + 1e-5f);
    const int t = threadIdx.x;
    const ushort2 xv = *reinterpret_cast<const ushort2*>(X + row * 512 + 2 * t);
    const float2 gg = *reinterpret_cast<const float2*>(g + 2 * t);
    const float2 bb = *reinterpret_cast<const float2*>(b + 2 * t);
    const float y0 = gelu_exact((bf2f(xv.x) - mu) * rs * gg.x + bb.x);
    const float y1 = gelu_exact((bf2f(xv.y) - mu) * rs * gg.y + bb.y);
    *reinterpret_cast<ushort2*>(X + row * 512 + 2 * t) = make_ushort2(f2bf(y0), f2bf(y1));
}

// ---------------- Attention: persistent, head<->XCD affinity (R19) ----------
__global__ __launch_bounds__(512) void attn_kernel(
    const u16* __restrict__ qh, const u16* __restrict__ kvb,
    const int* __restrict__ kidx, const int* __restrict__ ncnt,
    u16* __restrict__ ctx)
{
    const int head = blockIdx.x & 7;
    const int grp  = blockIdx.x >> 3;
    const int ngrp = gridDim.x >> 3;
    const int wv   = threadIdx.x >> 6;
    const int lane = threadIdx.x & 63;
    const int mi = lane & 7, dg = lane >> 3;
    const bool b0 = (mi & 1), b1 = (mi & 2), b2 = (mi & 4);
    const int doff = (b0 ? 4 : 0) + (b1 ? 2 : 0) + (b2 ? 1 : 0);
    const int hoff = head * 64 + dg * 8;

    for (int l0 = (grp * 8 + wv) * 2; l0 < 32768; l0 += ngrp * 16) {
        int cnt[2], idxv[2];
        bool act[2];
        u16x8 qv[2], kv[2], vv[2];
        size_t kvbase[2];
        #pragma unroll
        for (int u = 0; u < 2; ++u) {
            const int l = l0 + u;
            cnt[u] = ncnt[l];
            idxv[u] = kidx[l * 8 + mi];
            act[u] = (mi < cnt[u]);
            kvbase[u] = (size_t)idxv[u] * 1024 + hoff;
            qv[u] = *(const u16x8*)(qh + (size_t)l * 512 + hoff);
            if (act[u]) {
                kv[u] = *(const u16x8*)(kvb + kvbase[u]);
                vv[u] = *(const u16x8*)(kvb + kvbase[u] + 512);
            }
        }

        float p[2] = {0.0f, 0.0f};
        #pragma unroll
        for (int u = 0; u < 2; ++u)
            if (act[u])
                #pragma unroll
                for (int jj = 0; jj < 8; ++jj)
                    p[u] = fmaf(bf2f(qv[u][jj]), bf2f(kv[u][jj]), p[u]);
        #pragma unroll
        for (int u = 0; u < 2; ++u) {
            p[u] += __shfl_xor(p[u], 8);
            p[u] += __shfl_xor(p[u], 16);
            p[u] += __shfl_xor(p[u], 32);
        }

        float s[2], mx[2], e[2], den[2], wgt[2];
        #pragma unroll
        for (int u = 0; u < 2; ++u) {
            s[u] = act[u] ? p[u] * 0.125f : -3.402823466e38f;
            mx[u] = s[u];
        }
        #pragma unroll
        for (int u = 0; u < 2; ++u) {
            mx[u] = fmaxf(mx[u], __shfl_xor(mx[u], 1));
            mx[u] = fmaxf(mx[u], __shfl_xor(mx[u], 2));
            mx[u] = fmaxf(mx[u], __shfl_xor(mx[u], 4));
        }
        #pragma unroll
        for (int u = 0; u < 2; ++u) { e[u] = __expf(s[u] - mx[u]); den[u] = e[u]; }
        #pragma unroll
        for (int u = 0; u < 2; ++u) {
            den[u] += __shfl_xor(den[u], 1);
            den[u] += __shfl_xor(den[u], 2);
            den[u] += __shfl_xor(den[u], 4);
        }
        #pragma unroll
        for (int u = 0; u < 2; ++u) wgt[u] = e[u] / den[u];

        float c[2][8] = {};
        #pragma unroll
        for (int u = 0; u < 2; ++u)
            if (act[u])
                #pragma unroll
                for (int jj = 0; jj < 8; ++jj)
                    c[u][jj] = wgt[u] * bf2f(vv[u][jj]);

        // value-halving butterfly over mi (both lines interleaved)
        #pragma unroll
        for (int u = 0; u < 2; ++u)
            #pragma unroll
            for (int jj = 0; jj < 4; ++jj) {
                const float snd = b0 ? c[u][jj] : c[u][jj + 4];
                const float rec = __shfl_xor(snd, 1);
                c[u][jj] = (b0 ? c[u][jj + 4] : c[u][jj]) + rec;
            }
        #pragma unroll
        for (int u = 0; u < 2; ++u)
            #pragma unroll
            for (int jj = 0; jj < 2; ++jj) {
                const float snd = b1 ? c[u][jj] : c[u][jj + 2];
                const float rec = __shfl_xor(snd, 2);
                c[u][jj] = (b1 ? c[u][jj + 2] : c[u][jj]) + rec;
            }
        #pragma unroll
        for (int u = 0; u < 2; ++u) {
            const float snd = b2 ? c[u][0] : c[u][1];
            const float rec = __shfl_xor(snd, 4);
            c[u][0] = (b2 ? c[u][1] : c[u][0]) + rec;
        }
        #pragma unroll
        for (int u = 0; u < 2; ++u)
            ctx[(size_t)(l0 + u) * 512 + head * 64 + dg * 8 + doff] = f2bf(c[u][0]);
    }
}

// ---------------- Final: h2 = h1 + gelu(LN2(h2_raw)); sigmoid(head) ---------
__global__ __launch_bounds__(256) void final_head_s(
    const u16* __restrict__ h1, const u16* __restrict__ h2raw,
    const float* __restrict__ stats,
    const float* __restrict__ g, const float* __restrict__ b,
    const float* __restrict__ hw, const float* __restrict__ hb,
    float* __restrict__ out)
{
    __shared__ float sm[4];
    const size_t row = blockIdx.x;
    float s = 0.0f, q2 = 0.0f;
    #pragma unroll
    for (int cb = 0; cb < 8; ++cb) {
        s  += stats[(row * 8 + cb) * 2];
        q2 += stats[(row * 8 + cb) * 2 + 1];
    }
    const float mu = s * (1.0f / 512.0f);
    const float var = q2 * (1.0f / 512.0f) - mu * mu;
    const float rs = rsqrtf(var + 1e-5f);
    const int t = threadIdx.x;
    const ushort2 xv = *reinterpret_cast<const ushort2*>(h2raw + row * 512 + 2 * t);
    const ushort2 hv = *reinterpret_cast<const ushort2*>(h1 + row * 512 + 2 * t);
    const float2 gg = *reinterpret_cast<const float2*>(g + 2 * t);
    const float2 bb = *reinterpret_cast<const float2*>(b + 2 * t);
    const float2 hwv = *reinterpret_cast<const float2*>(hw + 2 * t);
    const float y0 = bf2f(hv.x) + gelu_exact((bf2f(xv.x) - mu) * rs * gg.x + bb.x);
    const float y1 = bf2f(hv.y) + gelu_exact((bf2f(xv.y) - mu) * rs * gg.y + bb.y);
    const float d = breduce1(y0 * hwv.x + y1 * hwv.y, sm);
    if (t == 0) out[row] = 1.0f / (1.0f + expf(-(d + hb[0])));
}

extern "C" void kernel_launch(void* const* d_in, const int* in_sizes, int n_in,
                              void* d_out, int out_size, void* d_ws, size_t ws_size,
                              hipStream_t stream)
{
    const float* lines  = (const float*)d_in[0];   // [32768,768]
    const float* blocks = (const float*)d_in[1];   // [8192,768]
    const float* Wq     = (const float*)d_in[2];   // [512,768]
    const float* Wkv    = (const float*)d_in[3];   // [512,768]
    const float* qn_g   = (const float*)d_in[4];
    const float* qn_b   = (const float*)d_in[5];
    const float* kvn_g  = (const float*)d_in[6];
    const float* kvn_b  = (const float*)d_in[7];
    const float* in_w   = (const float*)d_in[8];   // [1536,512]
    const float* in_b   = (const float*)d_in[9];   // [1536]
    const float* out_w  = (const float*)d_in[10];  // [512,512]
    const float* out_b  = (const float*)d_in[11];
    const float* p1_w   = (const float*)d_in[12];  // [512,1024]
    const float* p1_b   = (const float*)d_in[13];
    const float* ln1_g  = (const float*)d_in[14];
    const float* ln1_b  = (const float*)d_in[15];
    const float* p2_w   = (const float*)d_in[16];  // [512,512]
    const float* p2_b   = (const float*)d_in[17];
    const float* ln2_g  = (const float*)d_in[18];
    const float* ln2_b  = (const float*)d_in[19];
    const float* head_w = (const float*)d_in[20];  // [1,512]
    const float* head_b = (const float*)d_in[21];  // [1]
    const int*   kidx   = (const int*)d_in[22];    // [32768,8]
    const int*   ncnt   = (const int*)d_in[23];    // [32768]
    float* out = (float*)d_out;                    // [32768]

    // workspace layout (liveness-checked; Lb/Bb eliminated in R21):
    char* wsb = (char*)d_ws;
    u16* qb    = (u16*)(wsb);
    u16* qhb   = (u16*)(wsb + (32ull << 20));
    u16* ctxb  = (u16*)(wsb + (64ull << 20));
    u16* kvbb  = (u16*)(wsb + (96ull << 20));
    u16* bkvb  = (u16*)(wsb + (112ull << 20));
    float* stats_q   = (float*)(wsb + (120ull << 20));
    float* stats_h1  = (float*)(wsb + (124ull << 20));
    float* stats_h2  = (float*)(wsb + (128ull << 20));
    float* stats_bkv = (float*)(wsb + (132ull << 20));
    u16* Wqb   = (u16*)(wsb + (136ull << 20));
    u16* Wkvb  = Wqb + 512 * 768;
    u16* inwb  = Wkvb + 512 * 768;
    u16* p1cb  = inwb + 1536 * 512;                // [512][1024] combined p1a|W2
    u16* p2wb  = p1cb + 512 * 1024;
    float* bias2f = (float*)(p2wb + 512 * 512);

    // weights: one fused conversion launch (p1 cols 512.. overwritten by fold_w2)
    {
        CvtJobs j;
        const float* ss[5] = { Wq, Wkv, in_w, p1_w, p2_w };
        u16* dd[5] = { Wqb, Wkvb, inwb, p1cb, p2wb };
        const int nn[5] = { 512 * 768, 512 * 768, 1536 * 512, 512 * 1024, 512 * 512 };
        int c = 0;
        for (int k = 0; k < 5; ++k) { j.s[k] = ss[k]; j.d[k] = dd[k]; j.cum[k] = c; c += nn[k] / 4; }
        j.cum[5] = c;
        cvt_multi<<<(c + 255) / 256, 256, 0, stream>>>(j);
    }
    // fold out-proj into p1
    fold_w2<<<dim3(8, 8), 256, 0, stream>>>(p1_w, out_w, p1cb);
    fold_bias<<<512, 64, 0, stream>>>(p1_w, out_b, p1_b, bias2f);

    GemmJob JD = {};   // dummy

    // 1. MERGED (fp32-A direct): q_raw = lines@Wq^T (+stats)
    //                         || bkv_raw = blocks@Wkv^T (+stats)
    {
        GemmJob jq  = { nullptr, nullptr, lines,  768, 768, Wqb,  nullptr, qb,   512, stats_q,   4, 2048 };
        GemmJob jbk = { nullptr, nullptr, blocks, 768, 768, Wkvb, nullptr, bkvb, 512, stats_bkv, 4, 512 };
        gemm_bf16<1, true><<<2560, 256, 0, stream>>>(jq, jbk, 2048);
    }
    // 2. MERGED LN: q = LN(q_raw)  ||  bkv = LN(bkv_raw)
    ln_merged<<<32768 + 8192, 256, 0, stream>>>(
        qb, stats_q, qn_g, qn_b, 32768, bkvb, stats_bkv, kvn_g, kvn_b);
    // 3. MERGED: qh = q@wq_i^T+bq_i  ||  kvbb = bkv@[wk;wv]^T+[bk;bv]
    {
        GemmJob jqh = { qb,   nullptr, nullptr, 512, 512, inwb,             in_b,       qhb,  512,  nullptr, 4, 2048 };
        GemmJob jkv = { bkvb, nullptr, nullptr, 512, 512, inwb + 512 * 512, in_b + 512, kvbb, 1024, nullptr, 8, 1024 };
        gemm_bf16<0, false><<<3072, 256, 0, stream>>>(jqh, jkv, 2048);
    }
    // 4. ctx (attention, persistent grid, head<->XCD affinity)
    attn_kernel<<<2048, 512, 0, stream>>>(qhb, kvbb, kidx, ncnt, ctxb);
    // 5. h1_raw = q@p1a^T + ctx@W2^T + bias2  (+stats; into qhb)
    {
        GemmJob jh1 = { qb, ctxb, nullptr, 512, 1024, p1cb, bias2f, qhb, 512, stats_h1, 4, 2048 };
        gemm_bf16<2, true><<<2048, 256, 0, stream>>>(jh1, JD, 2048);
    }
    // 6. h1 = gelu(LN1(h1_raw)) in-place
    ln_rows_g<<<32768, 256, 0, stream>>>(qhb, stats_h1, ln1_g, ln1_b);
    // 7. h2_raw = h1@p2_w^T + p2_b  (+stats; into ctxb)
    {
        GemmJob jh2 = { qhb, nullptr, nullptr, 512, 512, p2wb, p2_b, ctxb, 512, stats_h2, 4, 2048 };
        gemm_bf16<0, true><<<2048, 256, 0, stream>>>(jh2, JD, 2048);
    }
    // 8. out = sigmoid((h1 + gelu(LN2(h2_raw))) . head_w + head_b)
    final_head_s<<<32768, 256, 0, stream>>>(qhb, ctxb, stats_h2, ln2_g, ln2_b,
                                            head_w, head_b, out);
}

// Round 23
// 402.686 us; speedup vs baseline: 1.0182x; 1.0182x over previous
//
#include <hip/hip_runtime.h>
#include <math.h>

// L=32768 lines, M=8 neighbors, B=8192 blocks, LIN=BIN=768, H=512, NH=8, DH=64

typedef unsigned short u16;
typedef unsigned int u32;
using bf16x8 = __attribute__((ext_vector_type(8))) __bf16;
using u16x8  = __attribute__((ext_vector_type(8))) u16;
using f32x4  = __attribute__((ext_vector_type(4))) float;

__device__ __forceinline__ u16 f2bf(float f) {
    u32 u = __builtin_bit_cast(u32, f);
    u32 r = u + 0x7fffu + ((u >> 16) & 1u);
    return (u16)(r >> 16);
}
__device__ __forceinline__ float bf2f(u16 h) {
    return __builtin_bit_cast(float, (u32)h << 16);
}
__device__ __forceinline__ float gelu_exact(float x) {
    return 0.5f * x * (1.0f + erff(x * 0.70710678118654752440f));
}

// Block-wide reduction of one value across 256 threads (4 waves).
__device__ __forceinline__ float breduce1(float s0, float* sm) {
    #pragma unroll
    for (int off = 32; off > 0; off >>= 1) s0 += __shfl_down(s0, off);
    const int lane = threadIdx.x & 63, w = threadIdx.x >> 6;
    __syncthreads();
    if (lane == 0) sm[w] = s0;
    __syncthreads();
    return sm[0] + sm[1] + sm[2] + sm[3];
}

// ---------------- merged fp32 -> bf16 conversion (lines + blocks) -----------
__global__ __launch_bounds__(256) void cvt_merged(
    const float* __restrict__ s0, u16* __restrict__ d0, int nq0,
    const float* __restrict__ s1, u16* __restrict__ d1)
{
    const int g = blockIdx.x * 256 + threadIdx.x;   // quad index
    const float* s; u16* d; int q;
    if (g < nq0) { s = s0; d = d0; q = g; }
    else         { s = s1; d = d1; q = g - nq0; }
    const float4 v = *reinterpret_cast<const float4*>(s + q * 4);
    ushort4 o = make_ushort4(f2bf(v.x), f2bf(v.y), f2bf(v.z), f2bf(v.w));
    *reinterpret_cast<ushort4*>(d + q * 4) = o;
}

// ---------------- fused multi-array conversion (weights) ----------------
struct CvtJobs {
    const float* s[5];
    u16* d[5];
    int cum[6];   // cumulative quad counts
};
__global__ __launch_bounds__(256) void cvt_multi(CvtJobs j)
{
    const int g = blockIdx.x * 256 + threadIdx.x;   // quad index
    if (g >= j.cum[5]) return;
    int seg = 0;
    #pragma unroll
    for (int k = 1; k < 5; ++k) seg += (g >= j.cum[k]);
    const int q = g - j.cum[seg];
    const float4 v = *reinterpret_cast<const float4*>(j.s[seg] + q * 4);
    ushort4 o = make_ushort4(f2bf(v.x), f2bf(v.y), f2bf(v.z), f2bf(v.w));
    *reinterpret_cast<ushort4*>(j.d[seg] + q * 4) = o;
}

// ---------------- W2 fold: W2 = p1b @ out_w  (fp32 in, bf16 out) ------------
__global__ __launch_bounds__(256) void fold_w2(
    const float* __restrict__ p1w, const float* __restrict__ outw,
    u16* __restrict__ p1cb)
{
    __shared__ float As[16][65];   // [k][i]
    __shared__ float Bs[16][65];   // [k][j]
    const int tx = threadIdx.x & 15, ty = threadIdx.x >> 4;
    const int i0 = blockIdx.y * 64, j0 = blockIdx.x * 64;
    const int lr = threadIdx.x >> 2;
    const int lc = (threadIdx.x & 3) * 4;
    const int kr = threadIdx.x >> 4;
    const int jc = (threadIdx.x & 15) * 4;
    float acc[4][4] = {};
    for (int k0 = 0; k0 < 512; k0 += 16) {
        const float4 av = *reinterpret_cast<const float4*>(
            p1w + (size_t)(i0 + lr) * 1024 + 512 + k0 + lc);
        As[lc + 0][lr] = av.x; As[lc + 1][lr] = av.y;
        As[lc + 2][lr] = av.z; As[lc + 3][lr] = av.w;
        const float4 bv = *reinterpret_cast<const float4*>(
            outw + (size_t)(k0 + kr) * 512 + j0 + jc);
        Bs[kr][jc + 0] = bv.x; Bs[kr][jc + 1] = bv.y;
        Bs[kr][jc + 2] = bv.z; Bs[kr][jc + 3] = bv.w;
        __syncthreads();
        #pragma unroll
        for (int kk = 0; kk < 16; ++kk) {
            float a[4], b[4];
            #pragma unroll
            for (int i = 0; i < 4; ++i) a[i] = As[kk][ty * 4 + i];
            #pragma unroll
            for (int jj = 0; jj < 4; ++jj) b[jj] = Bs[kk][tx * 4 + jj];
            #pragma unroll
            for (int i = 0; i < 4; ++i)
                #pragma unroll
                for (int jj = 0; jj < 4; ++jj)
                    acc[i][jj] = fmaf(a[i], b[jj], acc[i][jj]);
        }
        __syncthreads();
    }
    #pragma unroll
    for (int i = 0; i < 4; ++i)
        #pragma unroll
        for (int jj = 0; jj < 4; ++jj)
            p1cb[(size_t)(i0 + ty * 4 + i) * 1024 + 512 + j0 + tx * 4 + jj] =
                f2bf(acc[i][jj]);
}

// bias2[i] = p1_b[i] + sum_k p1_w[i][512+k] * out_b[k]
__global__ __launch_bounds__(64) void fold_bias(
    const float* __restrict__ p1w, const float* __restrict__ outb,
    const float* __restrict__ p1b, float* __restrict__ bias2)
{
    const int i = blockIdx.x, lane = threadIdx.x;
    float s = 0.0f;
    #pragma unroll
    for (int k = lane; k < 512; k += 64)
        s += p1w[(size_t)i * 1024 + 512 + k] * outb[k];
    #pragma unroll
    for (int off = 32; off > 0; off >>= 1) s += __shfl_down(s, off);
    if (lane == 0) bias2[i] = s + p1b[i];
}

// ---------------- bf16 MFMA GEMM, dual-job (R20) ----------------------------
// Two independent GEMMs packed into one launch: blocks [0,n0) run job0,
// [n0,n0+n1) run job1 -> the small job's blocks fill CUs left idle by the
// big job instead of serializing as a separate dispatch.
// Per job: 64x128 tile, BK=32, 4 waves, 2-buffer counted-vmcnt pipeline,
// T2 LDS XOR-swizzle (R18, verified), T1 XCD swizzle within job range.
// A_MODE: 0 = bf16 A; 2 = two bf16 sources split at column K1.
// STATS requires N==512 (nbx==4).
// R21 lesson (matches R7): reg-staged fp32-A with write-late costs more than
// the cvt pass it saves -- gload_lds-only staging is required for the
// pipeline to hold.
struct GemmJob {
    const u16* A1; const u16* A2; int K1; int K;
    const u16* W; const float* bias;
    u16* C; int N; float* stats;
    int nbx;     // N/128
    int nwg;     // total blocks (divisible by 8)
};

template<int A_MODE, bool STATS>
__global__ __launch_bounds__(256) void gemm_bf16(
    GemmJob j0, GemmJob j1, int n0)
{
    __shared__ __bf16 As[2 * 64 * 32];     // 8 KB
    __shared__ __bf16 Ws[2 * 128 * 32];    // 16 KB
    const int tid = threadIdx.x;
    const int w = tid >> 6, lane = tid & 63;

    GemmJob jb;
    int orig;
    if ((int)blockIdx.x < n0) { jb = j0; orig = blockIdx.x; }
    else                      { jb = j1; orig = blockIdx.x - n0; }

    // T1 swizzle within the job's block range (nwg divisible by 8)
    const u32 wgid = ((u32)orig & 7u) * ((u32)jb.nwg >> 3) + ((u32)orig >> 3);
    const int bx = (int)(wgid % (u32)jb.nbx);
    const int row0 = (int)(wgid / (u32)jb.nbx) * 64;
    const int col0 = bx * 128;
    const int K = jb.K, K1 = jb.K1, N = jb.N;

    const int wrow = (w >> 1) * 32, wcol = (w & 1) * 64;
    const int fr = lane & 15, fg = lane >> 4;
    const int fgx = fg ^ ((fr >> 1) & 3);   // swizzled 16B-slot index (in [0,4))

    // W staging geometry (128x32 bf16 tile, 2 chunks/wave), swizzled source
    int srow[2], scol[2], soff[2];
    #pragma unroll
    for (int c = 0; c < 2; ++c) {
        const int bo = w * 2048 + c * 1024 + lane * 16;
        srow[c] = bo >> 6;
        const int slot = (bo & 63) >> 4;                 // = lane & 3
        scol[c] = (slot ^ ((srow[c] >> 1) & 3)) * 8;     // in [0,32)
        soff[c] = (w * 2048 + c * 1024) >> 1;
    }
    // A staging geometry (64x32 bf16 tile, 1 chunk/wave)
    const int aoA = w * 1024 + lane * 16;
    const int srA = aoA >> 6;
    const int scA = (((aoA & 63) >> 4) ^ ((srA >> 1) & 3)) * 8;  // in [0,32)
    const int sofA = (w * 1024) >> 1;

    f32x4 acc[2][4] = {};

    auto stage_issue = [&](int k0, int buf) {
        const u16* asrc;
        if (A_MODE == 2 && k0 >= K1) {
            asrc = jb.A2 + (size_t)(row0 + srA) * (K - K1) + (k0 - K1) + scA;
        } else {
            const int ld = (A_MODE == 2) ? K1 : K;
            asrc = jb.A1 + (size_t)(row0 + srA) * ld + k0 + scA;
        }
        __builtin_amdgcn_global_load_lds(
            (const __attribute__((address_space(1))) u32*)asrc,
            (__attribute__((address_space(3))) u32*)(As + buf * 2048 + sofA),
            16, 0, 0);
        #pragma unroll
        for (int c = 0; c < 2; ++c) {
            const u16* wsrc = jb.W + (size_t)(col0 + srow[c]) * K + k0 + scol[c];
            __builtin_amdgcn_global_load_lds(
                (const __attribute__((address_space(1))) u32*)wsrc,
                (__attribute__((address_space(3))) u32*)(Ws + buf * 4096 + soff[c]),
                16, 0, 0);
        }
    };

    const int NT = K >> 5;           // >= 16 always here

    stage_issue(0, 0);

    int bufc = 0;
    for (int t = 0; t < NT; ++t) {
        if (t + 1 < NT) {
            stage_issue((t + 1) << 5, bufc ^ 1);
            asm volatile("s_waitcnt vmcnt(3)" ::: "memory");
        } else {
            asm volatile("s_waitcnt vmcnt(0)" ::: "memory");
        }
        __builtin_amdgcn_s_barrier();          // tile t fully in LDS for all waves
        __builtin_amdgcn_sched_barrier(0);

        bf16x8 af[2], bfr[4];
        #pragma unroll
        for (int m = 0; m < 2; ++m)
            af[m] = *(const bf16x8*)(As + bufc * 2048 + (wrow + m * 16 + fr) * 32 + fgx * 8);
        #pragma unroll
        for (int n = 0; n < 4; ++n)
            bfr[n] = *(const bf16x8*)(Ws + bufc * 4096 + (wcol + n * 16 + fr) * 32 + fgx * 8);
        #pragma unroll
        for (int m = 0; m < 2; ++m)
            #pragma unroll
            for (int n = 0; n < 4; ++n)
                acc[m][n] = __builtin_amdgcn_mfma_f32_16x16x32_bf16(
                    af[m], bfr[n], acc[m][n], 0, 0, 0);

        __builtin_amdgcn_s_barrier();          // all waves done reading buf t
        bufc ^= 1;
    }

    // bias add (pre-stats, pre-round)
    if (jb.bias) {
        #pragma unroll
        for (int n = 0; n < 4; ++n) {
            const float bvv = jb.bias[col0 + wcol + n * 16 + fr];
            #pragma unroll
            for (int m = 0; m < 2; ++m)
                #pragma unroll
                for (int r = 0; r < 4; ++r)
                    acc[m][n][r] += bvv;
        }
    }

    // C/D layout: col=lane&15, row=(lane>>4)*4+reg  [m89-verified]
    #pragma unroll
    for (int m = 0; m < 2; ++m)
        #pragma unroll
        for (int n = 0; n < 4; ++n) {
            const int col = col0 + wcol + n * 16 + fr;
            #pragma unroll
            for (int r = 0; r < 4; ++r) {
                const int row = row0 + wrow + m * 16 + fg * 4 + r;
                jb.C[(size_t)row * N + col] = f2bf(acc[m][n][r]);
            }
        }

    if (STATS) {
        float ps[2][4], pq[2][4];
        #pragma unroll
        for (int m = 0; m < 2; ++m)
            #pragma unroll
            for (int r = 0; r < 4; ++r) {
                float s = 0.0f, q2 = 0.0f;
                #pragma unroll
                for (int n = 0; n < 4; ++n) {
                    const float v = acc[m][n][r];
                    s += v; q2 = fmaf(v, v, q2);
                }
                ps[m][r] = s; pq[m][r] = q2;
            }
        #pragma unroll
        for (int off = 1; off < 16; off <<= 1)
            #pragma unroll
            for (int m = 0; m < 2; ++m)
                #pragma unroll
                for (int r = 0; r < 4; ++r) {
                    ps[m][r] += __shfl_xor(ps[m][r], off);
                    pq[m][r] += __shfl_xor(pq[m][r], off);
                }
        if (fr == 0) {
            const int cb = bx * 2 + (w & 1);
            #pragma unroll
            for (int m = 0; m < 2; ++m)
                #pragma unroll
                for (int r = 0; r < 4; ++r) {
                    const int row = row0 + wrow + m * 16 + fg * 4 + r;
                    *reinterpret_cast<float2*>(jb.stats + ((size_t)row * 8 + cb) * 2) =
                        make_float2(ps[m][r], pq[m][r]);
                }
        }
    }
}

// ---------------- merged Row LayerNorm (two row ranges, R20) ----------------
__global__ __launch_bounds__(256) void ln_merged(
    u16* __restrict__ X0, const float* __restrict__ st0,
    const float* __restrict__ g0, const float* __restrict__ b0, int n0,
    u16* __restrict__ X1, const float* __restrict__ st1,
    const float* __restrict__ g1, const float* __restrict__ b1)
{
    u16* X; const float* st; const float* g; const float* b; size_t row;
    if ((int)blockIdx.x < n0) { X = X0; st = st0; g = g0; b = b0; row = blockIdx.x; }
    else { X = X1; st = st1; g = g1; b = b1; row = blockIdx.x - n0; }
    float s = 0.0f, q2 = 0.0f;
    #pragma unroll
    for (int cb = 0; cb < 8; ++cb) {
        s  += st[(row * 8 + cb) * 2];
        q2 += st[(row * 8 + cb) * 2 + 1];
    }
    const float mu = s * (1.0f / 512.0f);
    const float var = q2 * (1.0f / 512.0f) - mu * mu;
    const float rs = rsqrtf(var + 1e-5f);
    const int t = threadIdx.x;
    const ushort2 xv = *reinterpret_cast<const ushort2*>(X + row * 512 + 2 * t);
    const float2 gg = *reinterpret_cast<const float2*>(g + 2 * t);
    const float2 bb = *reinterpret_cast<const float2*>(b + 2 * t);
    const float y0 = (bf2f(xv.x) - mu) * rs * gg.x + bb.x;
    const float y1 = (bf2f(xv.y) - mu) * rs * gg.y + bb.y;
    *reinterpret_cast<ushort2*>(X + row * 512 + 2 * t) = make_ushort2(f2bf(y0), f2bf(y1));
}

// ---------------- Row LayerNorm in-place with GELU (h1) ---------------------
__global__ __launch_bounds__(256) void ln_rows_g(
    u16* __restrict__ X, const float* __restrict__ stats,
    const float* __restrict__ g, const float* __restrict__ b)
{
    const size_t row = blockIdx.x;
    float s = 0.0f, q2 = 0.0f;
    #pragma unroll
    for (int cb = 0; cb < 8; ++cb) {
        s  += stats[(row * 8 + cb) * 2];
        q2 += stats[(row * 8 + cb) * 2 + 1];
    }
    const float mu = s * (1.0f / 512.0f);
    const float var = q2 * (1.0f / 512.0f) - mu * mu;
    const float rs = rsqrtf(var + 1e-5f);
    const int t = threadIdx.x;
    const ushort2 xv = *reinterpret_cast<const ushort2*>(X + row * 512 + 2 * t);
    const float2 gg = *reinterpret_cast<const float2*>(g + 2 * t);
    const float2 bb = *reinterpret_cast<const float2*>(b + 2 * t);
    const float y0 = gelu_exact((bf2f(xv.x) - mu) * rs * gg.x + bb.x);
    const float y1 = gelu_exact((bf2f(xv.y) - mu) * rs * gg.y + bb.y);
    *reinterpret_cast<ushort2*>(X + row * 512 + 2 * t) = make_ushort2(f2bf(y0), f2bf(y1));
}

// ---------------- Attention: persistent, head<->XCD affinity (R19) ----------
__global__ __launch_bounds__(512) void attn_kernel(
    const u16* __restrict__ qh, const u16* __restrict__ kvb,
    const int* __restrict__ kidx, const int* __restrict__ ncnt,
    u16* __restrict__ ctx)
{
    const int head = blockIdx.x & 7;
    const int grp  = blockIdx.x >> 3;
    const int ngrp = gridDim.x >> 3;
    const int wv   = threadIdx.x >> 6;
    const int lane = threadIdx.x & 63;
    const int mi = lane & 7, dg = lane >> 3;
    const bool b0 = (mi & 1), b1 = (mi & 2), b2 = (mi & 4);
    const int doff = (b0 ? 4 : 0) + (b1 ? 2 : 0) + (b2 ? 1 : 0);
    const int hoff = head * 64 + dg * 8;

    for (int l0 = (grp * 8 + wv) * 2; l0 < 32768; l0 += ngrp * 16) {
        int cnt[2], idxv[2];
        bool act[2];
        u16x8 qv[2], kv[2], vv[2];
        size_t kvbase[2];
        #pragma unroll
        for (int u = 0; u < 2; ++u) {
            const int l = l0 + u;
            cnt[u] = ncnt[l];
            idxv[u] = kidx[l * 8 + mi];
            act[u] = (mi < cnt[u]);
            kvbase[u] = (size_t)idxv[u] * 1024 + hoff;
            qv[u] = *(const u16x8*)(qh + (size_t)l * 512 + hoff);
            if (act[u]) {
                kv[u] = *(const u16x8*)(kvb + kvbase[u]);
                vv[u] = *(const u16x8*)(kvb + kvbase[u] + 512);
            }
        }

        float p[2] = {0.0f, 0.0f};
        #pragma unroll
        for (int u = 0; u < 2; ++u)
            if (act[u])
                #pragma unroll
                for (int jj = 0; jj < 8; ++jj)
                    p[u] = fmaf(bf2f(qv[u][jj]), bf2f(kv[u][jj]), p[u]);
        #pragma unroll
        for (int u = 0; u < 2; ++u) {
            p[u] += __shfl_xor(p[u], 8);
            p[u] += __shfl_xor(p[u], 16);
            p[u] += __shfl_xor(p[u], 32);
        }

        float s[2], mx[2], e[2], den[2], wgt[2];
        #pragma unroll
        for (int u = 0; u < 2; ++u) {
            s[u] = act[u] ? p[u] * 0.125f : -3.402823466e38f;
            mx[u] = s[u];
        }
        #pragma unroll
        for (int u = 0; u < 2; ++u) {
            mx[u] = fmaxf(mx[u], __shfl_xor(mx[u], 1));
            mx[u] = fmaxf(mx[u], __shfl_xor(mx[u], 2));
            mx[u] = fmaxf(mx[u], __shfl_xor(mx[u], 4));
        }
        #pragma unroll
        for (int u = 0; u < 2; ++u) { e[u] = __expf(s[u] - mx[u]); den[u] = e[u]; }
        #pragma unroll
        for (int u = 0; u < 2; ++u) {
            den[u] += __shfl_xor(den[u], 1);
            den[u] += __shfl_xor(den[u], 2);
            den[u] += __shfl_xor(den[u], 4);
        }
        #pragma unroll
        for (int u = 0; u < 2; ++u) wgt[u] = e[u] / den[u];

        float c[2][8] = {};
        #pragma unroll
        for (int u = 0; u < 2; ++u)
            if (act[u])
                #pragma unroll
                for (int jj = 0; jj < 8; ++jj)
                    c[u][jj] = wgt[u] * bf2f(vv[u][jj]);

        // value-halving butterfly over mi (both lines interleaved)
        #pragma unroll
        for (int u = 0; u < 2; ++u)
            #pragma unroll
            for (int jj = 0; jj < 4; ++jj) {
                const float snd = b0 ? c[u][jj] : c[u][jj + 4];
                const float rec = __shfl_xor(snd, 1);
                c[u][jj] = (b0 ? c[u][jj + 4] : c[u][jj]) + rec;
            }
        #pragma unroll
        for (int u = 0; u < 2; ++u)
            #pragma unroll
            for (int jj = 0; jj < 2; ++jj) {
                const float snd = b1 ? c[u][jj] : c[u][jj + 2];
                const float rec = __shfl_xor(snd, 2);
                c[u][jj] = (b1 ? c[u][jj + 2] : c[u][jj]) + rec;
            }
        #pragma unroll
        for (int u = 0; u < 2; ++u) {
            const float snd = b2 ? c[u][0] : c[u][1];
            const float rec = __shfl_xor(snd, 4);
            c[u][0] = (b2 ? c[u][1] : c[u][0]) + rec;
        }
        #pragma unroll
        for (int u = 0; u < 2; ++u)
            ctx[(size_t)(l0 + u) * 512 + head * 64 + dg * 8 + doff] = f2bf(c[u][0]);
    }
}

// ---------------- Final: h2 = h1 + gelu(LN2(h2_raw)); sigmoid(head) ---------
__global__ __launch_bounds__(256) void final_head_s(
    const u16* __restrict__ h1, const u16* __restrict__ h2raw,
    const float* __restrict__ stats,
    const float* __restrict__ g, const float* __restrict__ b,
    const float* __restrict__ hw, const float* __restrict__ hb,
    float* __restrict__ out)
{
    __shared__ float sm[4];
    const size_t row = blockIdx.x;
    float s = 0.0f, q2 = 0.0f;
    #pragma unroll
    for (int cb = 0; cb < 8; ++cb) {
        s  += stats[(row * 8 + cb) * 2];
        q2 += stats[(row * 8 + cb) * 2 + 1];
    }
    const float mu = s * (1.0f / 512.0f);
    const float var = q2 * (1.0f / 512.0f) - mu * mu;
    const float rs = rsqrtf(var + 1e-5f);
    const int t = threadIdx.x;
    const ushort2 xv = *reinterpret_cast<const ushort2*>(h2raw + row * 512 + 2 * t);
    const ushort2 hv = *reinterpret_cast<const ushort2*>(h1 + row * 512 + 2 * t);
    const float2 gg = *reinterpret_cast<const float2*>(g + 2 * t);
    const float2 bb = *reinterpret_cast<const float2*>(b + 2 * t);
    const float2 hwv = *reinterpret_cast<const float2*>(hw + 2 * t);
    const float y0 = bf2f(hv.x) + gelu_exact((bf2f(xv.x) - mu) * rs * gg.x + bb.x);
    const float y1 = bf2f(hv.y) + gelu_exact((bf2f(xv.y) - mu) * rs * gg.y + bb.y);
    const float d = breduce1(y0 * hwv.x + y1 * hwv.y, sm);
    if (t == 0) out[row] = 1.0f / (1.0f + expf(-(d + hb[0])));
}

extern "C" void kernel_launch(void* const* d_in, const int* in_sizes, int n_in,
                              void* d_out, int out_size, void* d_ws, size_t ws_size,
                              hipStream_t stream)
{
    const float* lines  = (const float*)d_in[0];   // [32768,768]
    const float* blocks = (const float*)d_in[1];   // [8192,768]
    const float* Wq     = (const float*)d_in[2];   // [512,768]
    const float* Wkv    = (const float*)d_in[3];   // [512,768]
    const float* qn_g   = (const float*)d_in[4];
    const float* qn_b   = (const float*)d_in[5];
    const float* kvn_g  = (const float*)d_in[6];
    const float* kvn_b  = (const float*)d_in[7];
    const float* in_w   = (const float*)d_in[8];   // [1536,512]
    const float* in_b   = (const float*)d_in[9];   // [1536]
    const float* out_w  = (const float*)d_in[10];  // [512,512]
    const float* out_b  = (const float*)d_in[11];
    const float* p1_w   = (const float*)d_in[12];  // [512,1024]
    const float* p1_b   = (const float*)d_in[13];
    const float* ln1_g  = (const float*)d_in[14];
    const float* ln1_b  = (const float*)d_in[15];
    const float* p2_w   = (const float*)d_in[16];  // [512,512]
    const float* p2_b   = (const float*)d_in[17];
    const float* ln2_g  = (const float*)d_in[18];
    const float* ln2_b  = (const float*)d_in[19];
    const float* head_w = (const float*)d_in[20];  // [1,512]
    const float* head_b = (const float*)d_in[21];  // [1]
    const int*   kidx   = (const int*)d_in[22];    // [32768,8]
    const int*   ncnt   = (const int*)d_in[23];    // [32768]
    float* out = (float*)d_out;                    // [32768]

    // workspace layout (liveness-checked; same as R13-R20):
    char* wsb = (char*)d_ws;
    u16* qb    = (u16*)(wsb);
    u16* qhb   = (u16*)(wsb + (32ull << 20));
    u16* Lb    = (u16*)(wsb + (32ull << 20));
    u16* ctxb  = (u16*)(wsb + (64ull << 20));
    u16* Bb    = (u16*)(wsb + (80ull << 20));
    u16* kvbb  = (u16*)(wsb + (96ull << 20));
    u16* bkvb  = (u16*)(wsb + (112ull << 20));
    float* stats_q   = (float*)(wsb + (120ull << 20));
    float* stats_h1  = (float*)(wsb + (124ull << 20));
    float* stats_h2  = (float*)(wsb + (128ull << 20));
    float* stats_bkv = (float*)(wsb + (132ull << 20));
    u16* Wqb   = (u16*)(wsb + (136ull << 20));
    u16* Wkvb  = Wqb + 512 * 768;
    u16* inwb  = Wkvb + 512 * 768;
    u16* p1cb  = inwb + 1536 * 512;                // [512][1024] combined p1a|W2
    u16* p2wb  = p1cb + 512 * 1024;
    float* bias2f = (float*)(p2wb + 512 * 512);

    // activations to bf16 (merged: lines + blocks)
    {
        const int nq_lines = 32768 * 768 / 4;   // 6291456
        const int nq_blocks = 8192 * 768 / 4;   // 1572864
        cvt_merged<<<(nq_lines + nq_blocks) / 256, 256, 0, stream>>>(
            lines, Lb, nq_lines, blocks, Bb);
    }
    // weights: one fused conversion launch (p1 cols 512.. overwritten by fold_w2)
    {
        CvtJobs j;
        const float* ss[5] = { Wq, Wkv, in_w, p1_w, p2_w };
        u16* dd[5] = { Wqb, Wkvb, inwb, p1cb, p2wb };
        const int nn[5] = { 512 * 768, 512 * 768, 1536 * 512, 512 * 1024, 512 * 512 };
        int c = 0;
        for (int k = 0; k < 5; ++k) { j.s[k] = ss[k]; j.d[k] = dd[k]; j.cum[k] = c; c += nn[k] / 4; }
        j.cum[5] = c;
        cvt_multi<<<(c + 255) / 256, 256, 0, stream>>>(j);
    }
    // fold out-proj into p1
    fold_w2<<<dim3(8, 8), 256, 0, stream>>>(p1_w, out_w, p1cb);
    fold_bias<<<512, 64, 0, stream>>>(p1_w, out_b, p1_b, bias2f);

    GemmJob JD = {};   // dummy

    // 1. MERGED: q_raw = lines@Wq^T (+stats)  ||  bkv_raw = blocks@Wkv^T (+stats)
    {
        GemmJob jq  = { Lb, nullptr, 768, 768, Wqb,  nullptr, qb,   512, stats_q,   4, 2048 };
        GemmJob jbk = { Bb, nullptr, 768, 768, Wkvb, nullptr, bkvb, 512, stats_bkv, 4, 512 };
        gemm_bf16<0, true><<<2560, 256, 0, stream>>>(jq, jbk, 2048);
    }
    // 2. MERGED LN: q = LN(q_raw)  ||  bkv = LN(bkv_raw)
    ln_merged<<<32768 + 8192, 256, 0, stream>>>(
        qb, stats_q, qn_g, qn_b, 32768, bkvb, stats_bkv, kvn_g, kvn_b);
    // 3. MERGED: qh = q@wq_i^T+bq_i  ||  kvbb = bkv@[wk;wv]^T+[bk;bv]
    {
        GemmJob jqh = { qb,   nullptr, 512, 512, inwb,             in_b,       qhb,  512,  nullptr, 4, 2048 };
        GemmJob jkv = { bkvb, nullptr, 512, 512, inwb + 512 * 512, in_b + 512, kvbb, 1024, nullptr, 8, 1024 };
        gemm_bf16<0, false><<<3072, 256, 0, stream>>>(jqh, jkv, 2048);
    }
    // 4. ctx (attention, persistent grid, head<->XCD affinity; Lb/Bb dead after 3)
    attn_kernel<<<2048, 512, 0, stream>>>(qhb, kvbb, kidx, ncnt, ctxb);
    // 5. h1_raw = q@p1a^T + ctx@W2^T + bias2  (+stats; into qhb)
    {
        GemmJob jh1 = { qb, ctxb, 512, 1024, p1cb, bias2f, qhb, 512, stats_h1, 4, 2048 };
        gemm_bf16<2, true><<<2048, 256, 0, stream>>>(jh1, JD, 2048);
    }
    // 6. h1 = gelu(LN1(h1_raw)) in-place
    ln_rows_g<<<32768, 256, 0, stream>>>(qhb, stats_h1, ln1_g, ln1_b);
    // 7. h2_raw = h1@p2_w^T + p2_b  (+stats; into ctxb)
    {
        GemmJob jh2 = { qhb, nullptr, 512, 512, p2wb, p2_b, ctxb, 512, stats_h2, 4, 2048 };
        gemm_bf16<0, true><<<2048, 256, 0, stream>>>(jh2, JD, 2048);
    }
    // 8. out = sigmoid((h1 + gelu(LN2(h2_raw))) . head_w + head_b)
    final_head_s<<<32768, 256, 0, stream>>>(qhb, ctxb, stats_h2, ln2_g, ln2_b,
                                            head_w, head_b, out);
}